// Round 12
// baseline (185.512 us; speedup 1.0000x reference)
//
#include <hip/hip_runtime.h>
#include <hip/hip_bf16.h>

#define B_SZ 4096
#define N_SZ 200

// workspace offsets (4-byte units)
#define OFF_BFRAG 0        // 12288 u32: W-fragments, 3 layers x 2kt x 4ct x 2(hi/lo) x 64 lanes x 4 u32
#define OFF_AW1BT 12288    // 4096 f32: aw1bT[d][k] = att_w1[k][64+d]  (for qc prep)
#define OFF_ERC   16384    // 384  f32: erc[r][k]
#define OFF_QC    16768    // B*64 f32: qc[b][k]
#define OFF_AGG   278912   // B*64 f32: unnormalized sum miu*f (atomic)
#define OFF_SC    541056   // B    f32: sum miu (atomic)
// total 545152 floats = 2.18 MB

typedef __attribute__((ext_vector_type(8))) __bf16 bf16x8;
typedef __attribute__((ext_vector_type(4))) __bf16 bf16x4;
typedef __attribute__((ext_vector_type(4))) float f32x4;
typedef __attribute__((ext_vector_type(4))) unsigned u32x4;

__device__ __forceinline__ void split2(float x, unsigned &hi, unsigned &lo) {
    unsigned u = __float_as_uint(x);
    hi = (u + 0x7FFFu + ((u >> 16) & 1u)) >> 16;
    float r = x - __uint_as_float(hi << 16);
    unsigned ul = __float_as_uint(r);
    lo = (ul + 0x7FFFu + ((ul >> 16) & 1u)) >> 16;
}

// ---------- prep (unchanged, proven) ----------
__global__ void prep1(const float* __restrict__ gu_w1, const float* __restrict__ gu_b1,
                      const float* __restrict__ gu_w2, const float* __restrict__ att_w1,
                      const float* __restrict__ rate_emb, float* __restrict__ ws) {
    int t = threadIdx.x;  // 1 block x 256
    unsigned* wsu = (unsigned*)ws;
    for (int i = t; i < 12288; i += 256) {
        int frag = i >> 8, within = i & 255, lane = within >> 2, r = within & 3;
        int hl = frag & 1, ct = (frag >> 1) & 3, kt = (frag >> 3) & 1, layer = frag >> 4;
        int col = ct * 16 + (lane & 15);
        int d0 = kt * 32 + 8 * (lane >> 4) + 2 * r;
        float w0, w1v;
        if (layer == 0)      { w0 = gu_w1[col * 128 + d0];  w1v = gu_w1[col * 128 + d0 + 1]; }
        else if (layer == 1) { w0 = gu_w2[col * 64 + d0];   w1v = gu_w2[col * 64 + d0 + 1]; }
        else                 { w0 = att_w1[col * 128 + d0]; w1v = att_w1[col * 128 + d0 + 1]; }
        unsigned h0, l0, h1, l1;
        split2(w0, h0, l0); split2(w1v, h1, l1);
        unsigned lo16 = hl ? l0 : h0;
        unsigned hi16 = hl ? l1 : h1;
        wsu[OFF_BFRAG + i] = lo16 | (hi16 << 16);
    }
    for (int i = t; i < 4096; i += 256) {
        int d = i >> 6, k = i & 63;
        ws[OFF_AW1BT + i] = att_w1[k * 128 + 64 + d];
    }
    for (int i = t; i < 384; i += 256) {
        int rr = i >> 6, k = i & 63;
        float a = gu_b1[k];
        for (int d = 0; d < 64; ++d)
            a += gu_w1[k * 128 + 64 + d] * rate_emb[rr * 64 + d];
        ws[OFF_ERC + i] = a;
    }
}

__global__ void prep2_qc(const int* __restrict__ iids, const float* __restrict__ item_emb,
                         const float* __restrict__ ws, float* __restrict__ qc) {
    int b = blockIdx.x, k = threadIdx.x;
    int iid = iids[b];
    const float* awbT = ws + OFF_AW1BT;
    const float* irow = item_emb + (size_t)iid * 64;
    float acc = 0.f;
    for (int d = 0; d < 64; ++d)
        acc = fmaf(awbT[d * 64 + k], irow[d], acc);
    qc[b * 64 + k] = acc;
}

// ---------- main: 1 wave per block, 2 tiles per wave, ~7 KB LDS ----------
// r10/r11 lessons: __launch_bounds__(64) is REQUIRED (without it hipcc budgets
// for 1024-thr workgroups -> 64-VGPR cap -> ~490 B/thread scratch spill).
// r12: activations are bf16-hi only (weights keep hi/lo splits) -> XL plane,
// lo-split VALU, and one MFMA per (ct,kt) deleted. Error attenuates ~1/sqrt(in)
// per layer; predicted absmax ~3-4.5e-3 < 6.29e-3 threshold.
__global__ __launch_bounds__(64) void fused_main(
    const int* __restrict__ pad, const float* __restrict__ user_emb,
    const float* __restrict__ gu_b2, const float* __restrict__ att_b1,
    const float* __restrict__ att_w2, const float* __restrict__ att_b2,
    const float* __restrict__ ws, float* __restrict__ aggbuf, float* __restrict__ scbuf) {

    __shared__ __align__(16) __bf16 XH[32 * 64];   // 2 tiles x 16 rows (hi plane only)
    __shared__ float erc_s[6 * 65];
    __shared__ int   rid_s[32];
    __shared__ float mask_s[32];
    __shared__ float b2_s[64], aw2_s[64], ab1_s[64], qc_s[64];

    const unsigned bx = blockIdx.x;
    const int b = bx / 7;
    const int c = bx - b * 7;          // chunk 0..6
    const bool has2 = (c < 6);         // chunk 6 holds only tile 12
    const int tid = threadIdx.x;       // 0..63 (one wave)
    const int lane = tid;
    const int lrow = lane & 15;
    const int lgrp = lane >> 4;
    const int lcol = lane & 15;
    const unsigned* __restrict__ bfrag = (const unsigned*)ws + OFF_BFRAG;
    const float ab2 = att_b2[0];

    // ---- per-block tiny staging (single wave; LDS deps compiler-ordered) ----
    b2_s[lane]  = gu_b2[lane];
    aw2_s[lane] = att_w2[lane];
    ab1_s[lane] = att_b1[lane];
    qc_s[lane]  = ws[OFF_QC + b * 64 + lane];
#pragma unroll
    for (int i = 0; i < 6; ++i) {
        int j = i * 64 + lane;
        erc_s[(j >> 6) * 65 + (j & 63)] = ws[OFF_ERC + j];
    }

    // ---- stage owned tiles: gather user_emb, bf16 cvt, swizzled LDS ----
    {
        const int dq = lane & 15;      // 4-col group
        const int rowt = lane >> 4;    // 0..3
#pragma unroll
        for (int lt = 0; lt < 2; ++lt) {
            if (lt == 0 || has2) {
                const int gt = 2 * c + lt;
#pragma unroll
                for (int p = 0; p < 4; ++p) {
                    int rr = p * 4 + rowt;         // row in tile
                    int lr = lt * 16 + rr;         // local row 0..31
                    int n  = gt * 16 + rr;         // global row
                    int uid = 0, rid = 0;
                    float4 v = make_float4(0.f, 0.f, 0.f, 0.f);
                    if (n < N_SZ) {
                        int2 pr = ((const int2*)pad)[b * N_SZ + n];
                        uid = pr.x; rid = pr.y;
                        v = *(const float4*)(user_emb + (size_t)uid * 64 + dq * 4);
                    }
                    bf16x4 hv = { (__bf16)v.x, (__bf16)v.y, (__bf16)v.z, (__bf16)v.w };
                    int g = dq >> 1;
                    int idx = lr * 64 + ((g ^ (lr & 7)) << 3) + (dq & 1) * 4;
                    *(bf16x4*)&XH[idx] = hv;
                    if (dq == 0) {
                        rid_s[lr]  = (n < N_SZ) ? rid : 0;
                        mask_s[lr] = (n < N_SZ && uid > 0) ? 1.f : 0.f;
                    }
                }
            }
        }
    }
    // no barrier: single wave; compiler inserts lgkmcnt waits for LDS reads.

    auto loadA = [&](const __bf16* P, int lt, bf16x8 A[2]) {
        int ln = lt * 16 + lrow;
        int s = ln & 7;
#pragma unroll
        for (int kt = 0; kt < 2; ++kt)
            A[kt] = *(const bf16x8*)&P[ln * 64 + (((kt * 4 + lgrp) ^ s) << 3)];
    };

#define LOAD_B(LAYER)                                                            \
    u32x4 bh[4][2], bl[4][2];                                                    \
    _Pragma("unroll")                                                            \
    for (int ct = 0; ct < 4; ++ct)                                               \
        _Pragma("unroll")                                                        \
        for (int kt = 0; kt < 2; ++kt) {                                         \
            int fb = (((LAYER) * 2 + kt) * 4 + ct) * 2;                          \
            bh[ct][kt] = *(const u32x4*)&bfrag[(fb + 0) * 256 + lane * 4];       \
            bl[ct][kt] = *(const u32x4*)&bfrag[(fb + 1) * 256 + lane * 4];       \
        }

// activations hi-only: 2 MFMAs per (ct,kt) — AH*BL (small term first), AH*BH
#define MFMA2(ACC)                                                               \
    _Pragma("unroll")                                                            \
    for (int ct = 0; ct < 4; ++ct)                                               \
        _Pragma("unroll")                                                        \
        for (int kt = 0; kt < 2; ++kt) {                                         \
            bf16x8 BH = __builtin_bit_cast(bf16x8, bh[ct][kt]);                  \
            bf16x8 BL = __builtin_bit_cast(bf16x8, bl[ct][kt]);                  \
            ACC[ct] = __builtin_amdgcn_mfma_f32_16x16x32_bf16(AH[kt], BL, ACC[ct], 0, 0, 0); \
            ACC[ct] = __builtin_amdgcn_mfma_f32_16x16x32_bf16(AH[kt], BH, ACC[ct], 0, 0, 0); \
        }

    f32x4 f_reg[2][4];   // both tiles' layer-2 outputs (exact f32 for agg)

    // ---- layer 1: h = relu(P @ W1a^T + erc[rid]) ----
    {
        LOAD_B(0)
#pragma unroll
        for (int lt = 0; lt < 2; ++lt) {
            if (lt == 0 || has2) {
                bf16x8 AH[2];
                loadA(XH, lt, AH);
                int nr[4], ridr[4];
#pragma unroll
                for (int r = 0; r < 4; ++r) { nr[r] = lt * 16 + lgrp * 4 + r; ridr[r] = rid_s[nr[r]]; }
                f32x4 acc[4];
#pragma unroll
                for (int ct = 0; ct < 4; ++ct) {
                    int k = ct * 16 + lcol;
#pragma unroll
                    for (int r = 0; r < 4; ++r) acc[ct][r] = erc_s[ridr[r] * 65 + k];
                }
                MFMA2(acc)
#pragma unroll
                for (int ct = 0; ct < 4; ++ct) {
                    int col = ct * 16 + lcol;
#pragma unroll
                    for (int r = 0; r < 4; ++r) {
                        float hv = fmaxf(acc[ct][r], 0.f);
                        int ln = nr[r];
                        int idx = ln * 64 + (((col >> 3) ^ (ln & 7)) << 3) + (col & 7);
                        XH[idx] = (__bf16)hv;
                    }
                }
            }
        }
    }

    // ---- layer 2: f = h @ W2^T + b2 (regs; hi stored for layer 3) ----
    {
        LOAD_B(1)
#pragma unroll
        for (int lt = 0; lt < 2; ++lt) {
            if (lt == 0 || has2) {
                bf16x8 AH[2];
                loadA(XH, lt, AH);
                f32x4 (&acc)[4] = f_reg[lt];
#pragma unroll
                for (int ct = 0; ct < 4; ++ct) {
                    float bb = b2_s[ct * 16 + lcol];
#pragma unroll
                    for (int r = 0; r < 4; ++r) acc[ct][r] = bb;
                }
                MFMA2(acc)
#pragma unroll
                for (int ct = 0; ct < 4; ++ct) {
                    int col = ct * 16 + lcol;
#pragma unroll
                    for (int r = 0; r < 4; ++r) {
                        int ln = lt * 16 + lgrp * 4 + r;
                        int idx = ln * 64 + (((col >> 3) ^ (ln & 7)) << 3) + (col & 7);
                        XH[idx] = (__bf16)acc[ct][r];   // layer-3 A operand
                    }
                }
            }
        }
    }

    // ---- layer 3 + miu + in-register agg ----
    float aggr[4] = { 0.f, 0.f, 0.f, 0.f };
    float swave = 0.f;
    {
        LOAD_B(2)
#pragma unroll
        for (int lt = 0; lt < 2; ++lt) {
            if (lt == 0 || has2) {
                bf16x8 AH[2];
                loadA(XH, lt, AH);
                float maskr[4];
#pragma unroll
                for (int r = 0; r < 4; ++r) maskr[r] = mask_s[lt * 16 + lgrp * 4 + r];
                f32x4 acc[4];
#pragma unroll
                for (int ct = 0; ct < 4; ++ct) {
                    int k = ct * 16 + lcol;
                    float bb = ab1_s[k], qq = qc_s[k];
#pragma unroll
                    for (int r = 0; r < 4; ++r) acc[ct][r] = fmaf(maskr[r], qq, bb);
                }
                MFMA2(acc)
                float pm[4] = { 0.f, 0.f, 0.f, 0.f };
#pragma unroll
                for (int ct = 0; ct < 4; ++ct) {
                    float w2v = aw2_s[ct * 16 + lcol];
#pragma unroll
                    for (int r = 0; r < 4; ++r)
                        pm[r] = fmaf(fmaxf(acc[ct][r], 0.f), w2v, pm[r]);
                }
#pragma unroll
                for (int off = 1; off <= 8; off <<= 1) {
#pragma unroll
                    for (int r = 0; r < 4; ++r) pm[r] += __shfl_xor(pm[r], off);
                }
                float miur[4];
#pragma unroll
                for (int r = 0; r < 4; ++r) {
                    miur[r] = __expf(pm[r] + ab2) * maskr[r];
                    swave += miur[r];
                }
#pragma unroll
                for (int ct = 0; ct < 4; ++ct)
#pragma unroll
                    for (int r = 0; r < 4; ++r)
                        aggr[ct] = fmaf(miur[r], f_reg[lt][ct][r], aggr[ct]);
            }
        }
    }

    // ---- reduce over lane groups, then atomic partials into ws ----
#pragma unroll
    for (int ct = 0; ct < 4; ++ct) {
        float v = aggr[ct];
        v += __shfl_xor(v, 16);
        v += __shfl_xor(v, 32);
        aggr[ct] = v;
    }
    swave += __shfl_xor(swave, 16);
    swave += __shfl_xor(swave, 32);
    if (lane < 16) {
#pragma unroll
        for (int ct = 0; ct < 4; ++ct)
            atomicAdd(&aggbuf[b * 64 + ct * 16 + lane], aggr[ct]);
    }
    if (lane == 0)
        atomicAdd(&scbuf[b], swave);
}

// ---- normalize + z = relu(agg @ agg_w^T + agg_b) ----
__global__ __launch_bounds__(256) void final_z(const float* __restrict__ aggbuf,
                                               const float* __restrict__ scbuf,
                                               const float* __restrict__ agg_w,
                                               const float* __restrict__ agg_b,
                                               float* __restrict__ out) {
    __shared__ float aws[64 * 65];
    int t = threadIdx.x;
    for (int idx = t; idx < 4096; idx += 256)
        aws[(idx >> 6) * 65 + (idx & 63)] = agg_w[idx];
    __syncthreads();
    int g = t >> 6, k = t & 63;
    for (int bi = 0; bi < 2; ++bi) {
        int b = blockIdx.x * 8 + g * 2 + bi;
        const float* arow = aggbuf + b * 64;   // wave-uniform -> s_load
        float inv = 1.f / (scbuf[b] + 1e-10f);
        float dot = 0.f;
        for (int d = 0; d < 64; ++d)
            dot = fmaf(aws[k * 65 + d], arow[d], dot);
        out[b * 64 + k] = fmaxf(fmaf(inv, dot, agg_b[k]), 0.f);
    }
}

extern "C" void kernel_launch(void* const* d_in, const int* in_sizes, int n_in,
                              void* d_out, int out_size, void* d_ws, size_t ws_size,
                              hipStream_t stream) {
    const int*   iids     = (const int*)d_in[0];
    const int*   pad      = (const int*)d_in[1];
    const float* user_emb = (const float*)d_in[2];
    const float* item_emb = (const float*)d_in[3];
    const float* rate_emb = (const float*)d_in[4];
    const float* gu_w1    = (const float*)d_in[5];
    const float* gu_b1    = (const float*)d_in[6];
    const float* gu_w2    = (const float*)d_in[7];
    const float* gu_b2    = (const float*)d_in[8];
    const float* att_w1   = (const float*)d_in[9];
    const float* att_b1   = (const float*)d_in[10];
    const float* att_w2   = (const float*)d_in[11];
    const float* att_b2   = (const float*)d_in[12];
    const float* agg_w    = (const float*)d_in[13];
    const float* agg_b    = (const float*)d_in[14];
    float* ws  = (float*)d_ws;
    float* out = (float*)d_out;

    hipLaunchKernelGGL(prep1, dim3(1), dim3(256), 0, stream,
                       gu_w1, gu_b1, gu_w2, att_w1, rate_emb, ws);
    hipLaunchKernelGGL(prep2_qc, dim3(B_SZ), dim3(64), 0, stream,
                       iids, item_emb, ws, ws + OFF_QC);
    hipMemsetAsync(ws + OFF_AGG, 0, (size_t)(B_SZ * 64 + B_SZ) * sizeof(float), stream);
    hipLaunchKernelGGL(fused_main, dim3(B_SZ * 7), dim3(64), 0, stream,
                       pad, user_emb, gu_b2, att_b1, att_w2, att_b2,
                       ws, ws + OFF_AGG, ws + OFF_SC);
    hipLaunchKernelGGL(final_z, dim3(B_SZ / 8), dim3(256), 0, stream,
                       ws + OFF_AGG, ws + OFF_SC, agg_w, agg_b, out);
}